// Round 1
// baseline (5960.160 us; speedup 1.0000x reference)
//
#include <hip/hip_runtime.h>
#include <hip/hip_fp16.h>
#include <cstdint>
#include <cstddef>

// Sizes (fixed by the problem)
// B=64, T=1024, I=64, H=256, G=3H=768, N=B*T=65536

typedef _Float16 half2_t __attribute__((ext_vector_type(2)));

__device__ __forceinline__ float fdot2f(unsigned int w, unsigned int h, float acc) {
#if defined(__has_builtin)
#if __has_builtin(__builtin_amdgcn_fdot2)
    return __builtin_amdgcn_fdot2(__builtin_bit_cast(half2_t, w),
                                  __builtin_bit_cast(half2_t, h), acc, false);
#else
    __half2 wv = __builtin_bit_cast(__half2, w);
    __half2 hv = __builtin_bit_cast(__half2, h);
    float2 wf = __half22float2(wv), hf = __half22float2(hv);
    return acc + wf.x * hf.x + wf.y * hf.y;
#endif
#else
    __half2 wv = __builtin_bit_cast(__half2, w);
    __half2 hv = __builtin_bit_cast(__half2, h);
    float2 wf = __half22float2(wv), hf = __half22float2(hv);
    return acc + wf.x * hf.x + wf.y * hf.y;
#endif
}

// Pack w_hh [768][256] f32 -> [768][128] of f16-pairs (adjacent k packed)
__global__ void pack_whh(const float* __restrict__ w1, const float* __restrict__ w2,
                         __half2* __restrict__ o1, __half2* __restrict__ o2) {
    int g = blockIdx.x;       // 0..767
    int k2 = threadIdx.x;     // 0..127
    const float* w = blockIdx.y ? w2 : w1;
    __half2* o = blockIdx.y ? o2 : o1;
    float a = w[g * 256 + 2 * k2];
    float b = w[g * 256 + 2 * k2 + 1];
    o[g * 128 + k2] = __floats2half2_rn(a, b);
}

// xw1 = x[65536,64] @ w_ih1[768,64]^T + b_ih1 -> f16 [65536,768]
__global__ __launch_bounds__(256)
void gemm_xw1(const float* __restrict__ A, const float* __restrict__ W,
              const float* __restrict__ bias, __half* __restrict__ out) {
    __shared__ float As[64][65];
    __shared__ float Ws[64][65];
    const int tid = threadIdx.x;
    const int n0 = blockIdx.y * 64, g0 = blockIdx.x * 64;
    for (int idx = tid; idx < 4096; idx += 256) {
        int r = idx >> 6, c = idx & 63;
        As[r][c] = A[(size_t)(n0 + r) * 64 + c];
        Ws[r][c] = W[(size_t)(g0 + r) * 64 + c];
    }
    __syncthreads();
    const int ty = tid >> 4, tx = tid & 15;
    float acc[4][4] = {};
    for (int k = 0; k < 64; ++k) {
        float a[4], w[4];
        #pragma unroll
        for (int i = 0; i < 4; ++i) a[i] = As[ty * 4 + i][k];
        #pragma unroll
        for (int jj = 0; jj < 4; ++jj) w[jj] = Ws[tx * 4 + jj][k];
        #pragma unroll
        for (int i = 0; i < 4; ++i)
            #pragma unroll
            for (int jj = 0; jj < 4; ++jj) acc[i][jj] += a[i] * w[jj];
    }
    #pragma unroll
    for (int jj = 0; jj < 4; ++jj) {
        float bb = bias[g0 + tx * 4 + jj];
        #pragma unroll
        for (int i = 0; i < 4; ++i)
            out[(size_t)(n0 + ty * 4 + i) * 768 + (g0 + tx * 4 + jj)] =
                __float2half(acc[i][jj] + bb);
    }
}

// xw2 = y1[65536,256](f16) @ w_eff[768,256](f16)^T + b_eff -> f16 [65536,768]
__global__ __launch_bounds__(256)
void gemm_xw2(const __half2* __restrict__ A, const __half2* __restrict__ W,
              const float* __restrict__ bias, __half* __restrict__ out) {
    __shared__ float As[64][65];
    __shared__ float Ws[64][65];
    const int tid = threadIdx.x;
    const int n0 = blockIdx.y * 64, g0 = blockIdx.x * 64;
    const int ty = tid >> 4, tx = tid & 15;
    float acc[4][4] = {};
    for (int kc = 0; kc < 4; ++kc) {
        __syncthreads();
        for (int idx = tid; idx < 2048; idx += 256) {
            int r = idx >> 5, c2 = idx & 31;
            float2 a2 = __half22float2(A[(size_t)(n0 + r) * 128 + kc * 32 + c2]);
            As[r][c2 * 2] = a2.x;
            As[r][c2 * 2 + 1] = a2.y;
            float2 w2v = __half22float2(W[(size_t)(g0 + r) * 128 + kc * 32 + c2]);
            Ws[r][c2 * 2] = w2v.x;
            Ws[r][c2 * 2 + 1] = w2v.y;
        }
        __syncthreads();
        for (int k = 0; k < 64; ++k) {
            float a[4], w[4];
            #pragma unroll
            for (int i = 0; i < 4; ++i) a[i] = As[ty * 4 + i][k];
            #pragma unroll
            for (int jj = 0; jj < 4; ++jj) w[jj] = Ws[tx * 4 + jj][k];
            #pragma unroll
            for (int i = 0; i < 4; ++i)
                #pragma unroll
                for (int jj = 0; jj < 4; ++jj) acc[i][jj] += a[i] * w[jj];
        }
    }
    #pragma unroll
    for (int jj = 0; jj < 4; ++jj) {
        float bb = bias[g0 + tx * 4 + jj];
        #pragma unroll
        for (int i = 0; i < 4; ++i)
            out[(size_t)(n0 + ty * 4 + i) * 768 + (g0 + tx * 4 + jj)] =
                __float2half(acc[i][jj] + bb);
    }
}

// GRU recurrence: one block per batch element; thread j owns hidden unit j
// (gate-rows j, j+256, j+512 held entirely in VGPRs as packed f16 pairs).
template<int LAYER>
__global__ __launch_bounds__(256, 1)
void rec_kernel(const __half2* __restrict__ wpack,  // [768][128] f16-pairs
                const float* __restrict__ b_hh,     // [768]
                const __half* __restrict__ xw,      // [64][1024][768]
                __half* __restrict__ y_out,         // LAYER==1: [64][1024][256]
                float* __restrict__ stats,          // sum[256], sumsq[256]
                float* __restrict__ mx_out,         // LAYER==2: [64][256]
                float* __restrict__ mn_out) {
    __shared__ __align__(16) __half2 h2s[128];
    const int j = threadIdx.x;   // 0..255
    const int b = blockIdx.x;    // 0..63

    uint4 wr[32], wz[32], wn[32];
    const uint4* wp = (const uint4*)wpack;
    #pragma unroll
    for (int q = 0; q < 32; ++q) wr[q] = wp[(size_t)j * 32 + q];
    #pragma unroll
    for (int q = 0; q < 32; ++q) wz[q] = wp[(size_t)(j + 256) * 32 + q];
    #pragma unroll
    for (int q = 0; q < 32; ++q) wn[q] = wp[(size_t)(j + 512) * 32 + q];

    const float br = b_hh[j], bz = b_hh[256 + j], bn = b_hh[512 + j];

    if (j < 128) h2s[j] = __floats2half2_rn(0.f, 0.f);

    float hprev = 0.f, ssum = 0.f, ssq = 0.f;
    float mx = -3.0e38f, mn = 3.0e38f;
    const __half* xwp = xw + (size_t)b * 1024 * 768;
    __half* yp = (LAYER == 1) ? (y_out + (size_t)b * 1024 * 256) : (__half*)nullptr;
    __syncthreads();

    for (int t = 0; t < 1024; ++t) {
        float xr = __half2float(xwp[j]);
        float xz = __half2float(xwp[256 + j]);
        float xn = __half2float(xwp[512 + j]);
        xwp += 768;

        float ar0 = br, ar1 = 0.f, az0 = bz, az1 = 0.f, an0 = bn, an1 = 0.f;
        const uint4* h4 = (const uint4*)h2s;
        #pragma unroll
        for (int q = 0; q < 32; ++q) {
            uint4 hq = h4[q];
            ar0 = fdot2f(wr[q].x, hq.x, ar0);
            az0 = fdot2f(wz[q].x, hq.x, az0);
            an0 = fdot2f(wn[q].x, hq.x, an0);
            ar1 = fdot2f(wr[q].y, hq.y, ar1);
            az1 = fdot2f(wz[q].y, hq.y, az1);
            an1 = fdot2f(wn[q].y, hq.y, an1);
            ar0 = fdot2f(wr[q].z, hq.z, ar0);
            az0 = fdot2f(wz[q].z, hq.z, az0);
            an0 = fdot2f(wn[q].z, hq.z, an0);
            ar1 = fdot2f(wr[q].w, hq.w, ar1);
            az1 = fdot2f(wz[q].w, hq.w, az1);
            an1 = fdot2f(wn[q].w, hq.w, an1);
        }
        float hr = ar0 + ar1, hz = az0 + az1, hn = an0 + an1;
        float r = 1.f / (1.f + __expf(-(xr + hr)));
        float z = 1.f / (1.f + __expf(-(xz + hz)));
        float pa = xn + r * hn;
        pa = fminf(fmaxf(pa, -15.f), 15.f);
        float e2 = __expf(2.f * pa);
        float nn = (e2 - 1.f) / (e2 + 1.f);
        float h = (1.f - z) * nn + z * hprev;
        hprev = h;
        ssum += h;
        ssq += h * h;
        if (LAYER == 2) { mx = fmaxf(mx, h); mn = fminf(mn, h); }
        __syncthreads();                      // all dots done reading h2s
        ((__half*)h2s)[j] = __float2half(h);  // publish h_t
        if (LAYER == 1) yp[(size_t)t * 256 + j] = __float2half(h);
        __syncthreads();                      // h2s ready for next step
    }
    atomicAdd(&stats[j], ssum);
    atomicAdd(&stats[256 + j], ssq);
    if (LAYER == 2) {
        mx_out[b * 256 + j] = mx;
        mn_out[b * 256 + j] = mn;
    }
}

// Fold BN1 (training-mode batch stats) into layer-2 input weights.
__global__ void fold_bn1(const float* __restrict__ w_ih2, const float* __restrict__ b_ih2,
                         const float* __restrict__ g1, const float* __restrict__ be1,
                         const float* __restrict__ stats1,
                         __half* __restrict__ w_eff, float* __restrict__ b_eff) {
    const int g = blockIdx.x, lane = threadIdx.x;  // 768 blocks x 64 threads
    const float invN = 1.f / 65536.f;
    float partial = 0.f;
    for (int c = lane; c < 256; c += 64) {
        float mu = stats1[c] * invN;
        float var = stats1[256 + c] * invN - mu * mu;
        float s = g1[c] * rsqrtf(var + 1e-5f);
        float sh = be1[c] - mu * s;
        float w = w_ih2[g * 256 + c];
        w_eff[g * 256 + c] = __float2half(w * s);
        partial += w * sh;
    }
    #pragma unroll
    for (int off = 32; off > 0; off >>= 1) partial += __shfl_down(partial, off);
    if (lane == 0) b_eff[g] = b_ih2[g] + partial;
}

// BN2 affine -> time max-pool (max if scale>=0 else min) -> tanh -> FC
__global__ void final_kernel(const float* __restrict__ stats2,
                             const float* __restrict__ mx, const float* __restrict__ mn,
                             const float* __restrict__ g2, const float* __restrict__ be2,
                             const float* __restrict__ w_fc, const float* __restrict__ b_fc,
                             float* __restrict__ out) {
    __shared__ float v[256];
    const int b = blockIdx.x, c = threadIdx.x;
    const float invN = 1.f / 65536.f;
    float mu = stats2[c] * invN;
    float var = stats2[256 + c] * invN - mu * mu;
    float s = g2[c] * rsqrtf(var + 1e-5f);
    float d = be2[c] - mu * s;
    float M = (s >= 0.f) ? mx[b * 256 + c] : mn[b * 256 + c];
    v[c] = tanhf(s * M + d);
    __syncthreads();
    if (c < 128) {
        float acc = b_fc[c];
        for (int k = 0; k < 256; ++k) acc += v[k] * w_fc[c * 256 + k];
        out[b * 128 + c] = acc;
    }
}

extern "C" void kernel_launch(void* const* d_in, const int* in_sizes, int n_in,
                              void* d_out, int out_size, void* d_ws, size_t ws_size,
                              hipStream_t stream) {
    const float* x     = (const float*)d_in[0];
    const float* w_ih1 = (const float*)d_in[1];
    const float* w_hh1 = (const float*)d_in[2];
    const float* b_ih1 = (const float*)d_in[3];
    const float* b_hh1 = (const float*)d_in[4];
    const float* g1    = (const float*)d_in[5];
    const float* be1   = (const float*)d_in[6];
    const float* w_ih2 = (const float*)d_in[7];
    const float* w_hh2 = (const float*)d_in[8];
    const float* b_ih2 = (const float*)d_in[9];
    const float* b_hh2 = (const float*)d_in[10];
    const float* g2    = (const float*)d_in[11];
    const float* be2   = (const float*)d_in[12];
    const float* w_fc  = (const float*)d_in[13];
    const float* b_fc  = (const float*)d_in[14];
    float* out = (float*)d_out;

    char* ws = (char*)d_ws;
    size_t off = 0;
    __half*  xw   = (__half*)(ws + off);  off += (size_t)65536 * 768 * 2;  // 100,663,296 (shared by both layers)
    __half*  y1   = (__half*)(ws + off);  off += (size_t)65536 * 256 * 2;  // 33,554,432
    __half2* wp1  = (__half2*)(ws + off); off += (size_t)768 * 128 * 4;    // 393,216
    __half2* wp2  = (__half2*)(ws + off); off += (size_t)768 * 128 * 4;
    __half*  weff = (__half*)(ws + off);  off += (size_t)768 * 256 * 2;
    float*   beff = (float*)(ws + off);   off += (size_t)768 * 4;
    float*   stats= (float*)(ws + off);   off += (size_t)1024 * 4;         // sum1,sq1,sum2,sq2
    float*   mx2  = (float*)(ws + off);   off += (size_t)64 * 256 * 4;
    float*   mn2  = (float*)(ws + off);   off += (size_t)64 * 256 * 4;
    // total ~129.3 MB

    hipMemsetAsync(stats, 0, 4096, stream);

    pack_whh<<<dim3(768, 2), dim3(128), 0, stream>>>(w_hh1, w_hh2, wp1, wp2);
    gemm_xw1<<<dim3(12, 1024), dim3(256), 0, stream>>>(x, w_ih1, b_ih1, xw);
    rec_kernel<1><<<dim3(64), dim3(256), 0, stream>>>(wp1, b_hh1, xw, y1, stats,
                                                      (float*)nullptr, (float*)nullptr);
    fold_bn1<<<dim3(768), dim3(64), 0, stream>>>(w_ih2, b_ih2, g1, be1, stats, weff, beff);
    gemm_xw2<<<dim3(12, 1024), dim3(256), 0, stream>>>((const __half2*)y1, (const __half2*)weff,
                                                       beff, xw);
    rec_kernel<2><<<dim3(64), dim3(256), 0, stream>>>(wp2, b_hh2, xw, (__half*)nullptr,
                                                      stats + 512, mx2, mn2);
    final_kernel<<<dim3(64), dim3(256), 0, stream>>>(stats + 512, mx2, mn2, g2, be2,
                                                     w_fc, b_fc, out);
}

// Round 2
// 4613.645 us; speedup vs baseline: 1.2919x; 1.2919x over previous
//
#include <hip/hip_runtime.h>
#include <hip/hip_fp16.h>
#include <cstdint>
#include <cstddef>

// Sizes (fixed by the problem)
// B=64, T=1024, I=64, H=256, G=3H=768, N=B*T=65536

typedef _Float16 half2_t __attribute__((ext_vector_type(2)));

__device__ __forceinline__ float fdot2f(unsigned int w, unsigned int h, float acc) {
#if defined(__has_builtin)
#if __has_builtin(__builtin_amdgcn_fdot2)
    return __builtin_amdgcn_fdot2(__builtin_bit_cast(half2_t, w),
                                  __builtin_bit_cast(half2_t, h), acc, false);
#else
    __half2 wv = __builtin_bit_cast(__half2, w);
    __half2 hv = __builtin_bit_cast(__half2, h);
    float2 wf = __half22float2(wv), hf = __half22float2(hv);
    return acc + wf.x * hf.x + wf.y * hf.y;
#endif
#else
    __half2 wv = __builtin_bit_cast(__half2, w);
    __half2 hv = __builtin_bit_cast(__half2, h);
    float2 wf = __half22float2(wv), hf = __half22float2(hv);
    return acc + wf.x * hf.x + wf.y * hf.y;
#endif
}

// Pack w_hh [768][256] f32 -> [768][128] of f16-pairs (adjacent k packed)
__global__ void pack_whh(const float* __restrict__ w1, const float* __restrict__ w2,
                         __half2* __restrict__ o1, __half2* __restrict__ o2) {
    int g = blockIdx.x;       // 0..767
    int k2 = threadIdx.x;     // 0..127
    const float* w = blockIdx.y ? w2 : w1;
    __half2* o = blockIdx.y ? o2 : o1;
    float a = w[g * 256 + 2 * k2];
    float b = w[g * 256 + 2 * k2 + 1];
    o[g * 128 + k2] = __floats2half2_rn(a, b);
}

// xw1 = x[65536,64] @ w_ih1[768,64]^T + b_ih1 -> f16 [65536,768]
__global__ __launch_bounds__(256)
void gemm_xw1(const float* __restrict__ A, const float* __restrict__ W,
              const float* __restrict__ bias, __half* __restrict__ out) {
    __shared__ float As[64][65];
    __shared__ float Ws[64][65];
    const int tid = threadIdx.x;
    const int n0 = blockIdx.y * 64, g0 = blockIdx.x * 64;
    for (int idx = tid; idx < 4096; idx += 256) {
        int r = idx >> 6, c = idx & 63;
        As[r][c] = A[(size_t)(n0 + r) * 64 + c];
        Ws[r][c] = W[(size_t)(g0 + r) * 64 + c];
    }
    __syncthreads();
    const int ty = tid >> 4, tx = tid & 15;
    float acc[4][4] = {};
    for (int k = 0; k < 64; ++k) {
        float a[4], w[4];
        #pragma unroll
        for (int i = 0; i < 4; ++i) a[i] = As[ty * 4 + i][k];
        #pragma unroll
        for (int jj = 0; jj < 4; ++jj) w[jj] = Ws[tx * 4 + jj][k];
        #pragma unroll
        for (int i = 0; i < 4; ++i)
            #pragma unroll
            for (int jj = 0; jj < 4; ++jj) acc[i][jj] += a[i] * w[jj];
    }
    #pragma unroll
    for (int jj = 0; jj < 4; ++jj) {
        float bb = bias[g0 + tx * 4 + jj];
        #pragma unroll
        for (int i = 0; i < 4; ++i)
            out[(size_t)(n0 + ty * 4 + i) * 768 + (g0 + tx * 4 + jj)] =
                __float2half(acc[i][jj] + bb);
    }
}

// xw2 = y1[65536,256](f16) @ w_eff[768,256](f16)^T + b_eff -> f16 [65536,768]
// half2-packed K: halves LDS reads and multiply instruction count vs f32 version.
__global__ __launch_bounds__(256)
void gemm_xw2(const __half2* __restrict__ A, const __half2* __restrict__ W,
              const float* __restrict__ bias, __half* __restrict__ out) {
    __shared__ __half2 As[64][33];
    __shared__ __half2 Ws[64][33];
    const int tid = threadIdx.x;
    const int n0 = blockIdx.y * 64, g0 = blockIdx.x * 64;
    const int ty = tid >> 4, tx = tid & 15;
    float acc[4][4] = {};
    for (int kc = 0; kc < 4; ++kc) {
        __syncthreads();
        for (int idx = tid; idx < 2048; idx += 256) {
            int r = idx >> 5, c2 = idx & 31;
            As[r][c2] = A[(size_t)(n0 + r) * 128 + kc * 32 + c2];
            Ws[r][c2] = W[(size_t)(g0 + r) * 128 + kc * 32 + c2];
        }
        __syncthreads();
        #pragma unroll 8
        for (int k2 = 0; k2 < 32; ++k2) {
            unsigned int a2[4], w2[4];
            #pragma unroll
            for (int i = 0; i < 4; ++i)
                a2[i] = __builtin_bit_cast(unsigned int, As[ty * 4 + i][k2]);
            #pragma unroll
            for (int jj = 0; jj < 4; ++jj)
                w2[jj] = __builtin_bit_cast(unsigned int, Ws[tx * 4 + jj][k2]);
            #pragma unroll
            for (int i = 0; i < 4; ++i)
                #pragma unroll
                for (int jj = 0; jj < 4; ++jj)
                    acc[i][jj] = fdot2f(w2[jj], a2[i], acc[i][jj]);
        }
    }
    #pragma unroll
    for (int jj = 0; jj < 4; ++jj) {
        float bb = bias[g0 + tx * 4 + jj];
        #pragma unroll
        for (int i = 0; i < 4; ++i)
            out[(size_t)(n0 + ty * 4 + i) * 768 + (g0 + tx * 4 + jj)] =
                __float2half(acc[i][jj] + bb);
    }
}

// GRU recurrence: one block per batch element; thread j owns hidden unit j
// (gate-rows j, j+256, j+512 held entirely in VGPRs/AGPRs as packed f16 pairs).
// Latency fixes: xw register double-buffer (prefetch t+1 during t), single
// barrier per step via double-buffered h in LDS, y-store moved off the
// pre-barrier critical path.
template<int LAYER>
__global__ __launch_bounds__(256, 1)
void rec_kernel(const __half2* __restrict__ wpack,  // [768][128] f16-pairs
                const float* __restrict__ b_hh,     // [768]
                const __half* __restrict__ xw,      // [64][1024][768]
                __half* __restrict__ y_out,         // LAYER==1: [64][1024][256]
                float* __restrict__ stats,          // sum[256], sumsq[256]
                float* __restrict__ mx_out,         // LAYER==2: [64][256]
                float* __restrict__ mn_out) {
    __shared__ __align__(16) __half2 hbuf[2][128];
    const int j = threadIdx.x;   // 0..255
    const int b = blockIdx.x;    // 0..63

    uint4 wr[32], wz[32], wn[32];
    const uint4* wp = (const uint4*)wpack;
    #pragma unroll
    for (int q = 0; q < 32; ++q) wr[q] = wp[(size_t)j * 32 + q];
    #pragma unroll
    for (int q = 0; q < 32; ++q) wz[q] = wp[(size_t)(j + 256) * 32 + q];
    #pragma unroll
    for (int q = 0; q < 32; ++q) wn[q] = wp[(size_t)(j + 512) * 32 + q];

    const float br = b_hh[j], bz = b_hh[256 + j], bn = b_hh[512 + j];

    if (j < 128) hbuf[0][j] = __floats2half2_rn(0.f, 0.f);

    float hprev = 0.f, ssum = 0.f, ssq = 0.f;
    float mx = -3.0e38f, mn = 3.0e38f;
    const __half* xwp = xw + (size_t)b * 1024 * 768;
    __half* yp = (LAYER == 1) ? (y_out + (size_t)b * 1024 * 256) : (__half*)nullptr;

    // prefetch t=0
    __half nxr = xwp[j], nxz = xwp[256 + j], nxn = xwp[512 + j];
    __half yhalf = __float2half(0.f);
    __syncthreads();

    for (int t = 0; t < 1024; ++t) {
        float xr = __half2float(nxr);
        float xz = __half2float(nxz);
        float xn = __half2float(nxn);
        // prefetch t+1 (t=1023 over-read lands in the adjacent y1 ws region; discarded)
        const __half* xq = xwp + (size_t)(t + 1) * 768;
        nxr = xq[j]; nxz = xq[256 + j]; nxn = xq[512 + j];
        // store h_{t-1}: overlaps with the dot phase below
        if (LAYER == 1 && t) yp[(size_t)(t - 1) * 256 + j] = yhalf;

        float ar0 = br, ar1 = 0.f, az0 = bz, az1 = 0.f, an0 = bn, an1 = 0.f;
        const uint4* h4 = (const uint4*)hbuf[t & 1];
        #pragma unroll
        for (int q = 0; q < 32; ++q) {
            uint4 hq = h4[q];
            ar0 = fdot2f(wr[q].x, hq.x, ar0);
            az0 = fdot2f(wz[q].x, hq.x, az0);
            an0 = fdot2f(wn[q].x, hq.x, an0);
            ar1 = fdot2f(wr[q].y, hq.y, ar1);
            az1 = fdot2f(wz[q].y, hq.y, az1);
            an1 = fdot2f(wn[q].y, hq.y, an1);
            ar0 = fdot2f(wr[q].z, hq.z, ar0);
            az0 = fdot2f(wz[q].z, hq.z, az0);
            an0 = fdot2f(wn[q].z, hq.z, an0);
            ar1 = fdot2f(wr[q].w, hq.w, ar1);
            az1 = fdot2f(wz[q].w, hq.w, az1);
            an1 = fdot2f(wn[q].w, hq.w, an1);
        }
        float hr = ar0 + ar1, hz = az0 + az1, hn = an0 + an1;
        float r = 1.f / (1.f + __expf(-(xr + hr)));
        float z = 1.f / (1.f + __expf(-(xz + hz)));
        float pa = xn + r * hn;
        pa = fminf(fmaxf(pa, -15.f), 15.f);
        float e2 = __expf(2.f * pa);
        float nn = (e2 - 1.f) / (e2 + 1.f);
        float h = (1.f - z) * nn + z * hprev;
        hprev = h;
        ssum += h;
        ssq += h * h;
        if (LAYER == 2) { mx = fmaxf(mx, h); mn = fminf(mn, h); }
        yhalf = __float2half(h);
        ((__half*)hbuf[(t + 1) & 1])[j] = yhalf;   // disjoint from read buffer
        __syncthreads();                           // single barrier per step
    }
    if (LAYER == 1) yp[(size_t)1023 * 256 + j] = yhalf;
    atomicAdd(&stats[j], ssum);
    atomicAdd(&stats[256 + j], ssq);
    if (LAYER == 2) {
        mx_out[b * 256 + j] = mx;
        mn_out[b * 256 + j] = mn;
    }
}

// Fold BN1 (training-mode batch stats) into layer-2 input weights.
__global__ void fold_bn1(const float* __restrict__ w_ih2, const float* __restrict__ b_ih2,
                         const float* __restrict__ g1, const float* __restrict__ be1,
                         const float* __restrict__ stats1,
                         __half* __restrict__ w_eff, float* __restrict__ b_eff) {
    const int g = blockIdx.x, lane = threadIdx.x;  // 768 blocks x 64 threads
    const float invN = 1.f / 65536.f;
    float partial = 0.f;
    for (int c = lane; c < 256; c += 64) {
        float mu = stats1[c] * invN;
        float var = stats1[256 + c] * invN - mu * mu;
        float s = g1[c] * rsqrtf(var + 1e-5f);
        float sh = be1[c] - mu * s;
        float w = w_ih2[g * 256 + c];
        w_eff[g * 256 + c] = __float2half(w * s);
        partial += w * sh;
    }
    #pragma unroll
    for (int off = 32; off > 0; off >>= 1) partial += __shfl_down(partial, off);
    if (lane == 0) b_eff[g] = b_ih2[g] + partial;
}

// BN2 affine -> time max-pool (max if scale>=0 else min) -> tanh -> FC
__global__ void final_kernel(const float* __restrict__ stats2,
                             const float* __restrict__ mx, const float* __restrict__ mn,
                             const float* __restrict__ g2, const float* __restrict__ be2,
                             const float* __restrict__ w_fc, const float* __restrict__ b_fc,
                             float* __restrict__ out) {
    __shared__ float v[256];
    const int b = blockIdx.x, c = threadIdx.x;
    const float invN = 1.f / 65536.f;
    float mu = stats2[c] * invN;
    float var = stats2[256 + c] * invN - mu * mu;
    float s = g2[c] * rsqrtf(var + 1e-5f);
    float d = be2[c] - mu * s;
    float M = (s >= 0.f) ? mx[b * 256 + c] : mn[b * 256 + c];
    v[c] = tanhf(s * M + d);
    __syncthreads();
    if (c < 128) {
        float acc = b_fc[c];
        for (int k = 0; k < 256; ++k) acc += v[k] * w_fc[c * 256 + k];
        out[b * 128 + c] = acc;
    }
}

extern "C" void kernel_launch(void* const* d_in, const int* in_sizes, int n_in,
                              void* d_out, int out_size, void* d_ws, size_t ws_size,
                              hipStream_t stream) {
    const float* x     = (const float*)d_in[0];
    const float* w_ih1 = (const float*)d_in[1];
    const float* w_hh1 = (const float*)d_in[2];
    const float* b_ih1 = (const float*)d_in[3];
    const float* b_hh1 = (const float*)d_in[4];
    const float* g1    = (const float*)d_in[5];
    const float* be1   = (const float*)d_in[6];
    const float* w_ih2 = (const float*)d_in[7];
    const float* w_hh2 = (const float*)d_in[8];
    const float* b_ih2 = (const float*)d_in[9];
    const float* b_hh2 = (const float*)d_in[10];
    const float* g2    = (const float*)d_in[11];
    const float* be2   = (const float*)d_in[12];
    const float* w_fc  = (const float*)d_in[13];
    const float* b_fc  = (const float*)d_in[14];
    float* out = (float*)d_out;

    char* ws = (char*)d_ws;
    size_t off = 0;
    __half*  xw   = (__half*)(ws + off);  off += (size_t)65536 * 768 * 2;  // 100,663,296 (shared by both layers)
    __half*  y1   = (__half*)(ws + off);  off += (size_t)65536 * 256 * 2;  // 33,554,432
    __half2* wp1  = (__half2*)(ws + off); off += (size_t)768 * 128 * 4;    // 393,216
    __half2* wp2  = (__half2*)(ws + off); off += (size_t)768 * 128 * 4;
    __half*  weff = (__half*)(ws + off);  off += (size_t)768 * 256 * 2;
    float*   beff = (float*)(ws + off);   off += (size_t)768 * 4;
    float*   stats= (float*)(ws + off);   off += (size_t)1024 * 4;         // sum1,sq1,sum2,sq2
    float*   mx2  = (float*)(ws + off);   off += (size_t)64 * 256 * 4;
    float*   mn2  = (float*)(ws + off);   off += (size_t)64 * 256 * 4;
    // total ~129.3 MB

    hipMemsetAsync(stats, 0, 4096, stream);

    pack_whh<<<dim3(768, 2), dim3(128), 0, stream>>>(w_hh1, w_hh2, wp1, wp2);
    gemm_xw1<<<dim3(12, 1024), dim3(256), 0, stream>>>(x, w_ih1, b_ih1, xw);
    rec_kernel<1><<<dim3(64), dim3(256), 0, stream>>>(wp1, b_hh1, xw, y1, stats,
                                                      (float*)nullptr, (float*)nullptr);
    fold_bn1<<<dim3(768), dim3(64), 0, stream>>>(w_ih2, b_ih2, g1, be1, stats, weff, beff);
    gemm_xw2<<<dim3(12, 1024), dim3(256), 0, stream>>>((const __half2*)y1, (const __half2*)weff,
                                                       beff, xw);
    rec_kernel<2><<<dim3(64), dim3(256), 0, stream>>>(wp2, b_hh2, xw, (__half*)nullptr,
                                                      stats + 512, mx2, mn2);
    final_kernel<<<dim3(64), dim3(256), 0, stream>>>(stats + 512, mx2, mn2, g2, be2,
                                                     w_fc, b_fc, out);
}